// Round 1
// baseline (1727.105 us; speedup 1.0000x reference)
//
#include <hip/hip_runtime.h>
#include <stdint.h>

typedef __attribute__((ext_vector_type(4))) float f32x4;
typedef __attribute__((ext_vector_type(8))) short s16x8;
typedef __attribute__((ext_vector_type(4))) unsigned int u32x4;

#define NB 64
#define NT 256
// E = H = 512

// ---- ws layout (bytes) ----
static constexpr size_t XL_OFF  = 0;                                   // bf16 [16384][512]
static constexpr size_t XR_OFF  = XL_OFF + (size_t)16384*512*2;        // bf16 [16384][512]
static constexpr size_t W1T_OFF = XR_OFF + (size_t)16384*512*2;        // bf16 [2][512][512] (n-major)
static constexpr size_t W2T_OFF = W1T_OFF + (size_t)2*512*512*2;       // bf16 [2][512][512] (col-major)
static constexpr size_t EXCH_OFF= W2T_OFF + (size_t)2*512*512*2;       // bf16 [2][4][2][16][512]
static constexpr size_t FLAG_OFF= EXCH_OFF + (size_t)2*4*2*16*512*2;   // int [2][4][8]

__device__ __forceinline__ unsigned short f2bf(float f) {
  unsigned u = __builtin_bit_cast(unsigned, f);
  u += 0x7fffu + ((u >> 16) & 1u);
  return (unsigned short)(u >> 16);
}

// ---------------- prep: transpose weights to bf16 ----------------
__global__ void k_prep_w(const float* __restrict__ Wl1, const float* __restrict__ Wl2,
                         const float* __restrict__ Wr1, const float* __restrict__ Wr2,
                         unsigned short* __restrict__ W1T, unsigned short* __restrict__ W2T) {
  __shared__ float tile[64][65];
  int bid = blockIdx.x;            // 256 blocks
  int m  = bid >> 7;               // 0: W1, 1: W2
  int s  = (bid >> 6) & 1;         // side
  int t8 = bid & 63;
  int tr = t8 >> 3, tc = t8 & 7;   // k-tile, n-tile
  const float* src = (m == 0) ? (s ? Wr1 : Wl1) : (s ? Wr2 : Wl2);
  unsigned short* dst = ((m == 0) ? W1T : W2T) + (size_t)s*262144;
  int tid = threadIdx.x;
  int j = tid & 63, i0 = (tid >> 6) << 4;
  #pragma unroll
  for (int i = 0; i < 16; ++i)
    tile[i0 + i][j] = src[(size_t)(tr*64 + i0 + i)*512 + tc*64 + j];
  __syncthreads();
  #pragma unroll
  for (int i = 0; i < 16; ++i) {
    int n = tc*64 + i0 + i;
    int k = tr*64 + j;
    dst[(size_t)n*512 + k] = f2bf(tile[j][i0 + i]);   // out[n][k] = in[k][n]
  }
}

// ---------------- prep: states into X row 0, zero exch/flags ----------------
__global__ void k_prep_misc(const float* __restrict__ lst, const float* __restrict__ rst,
                            unsigned short* __restrict__ Xl, unsigned short* __restrict__ Xr,
                            unsigned int* __restrict__ exch_w, int* __restrict__ flags) {
  int gid = blockIdx.x * blockDim.x + threadIdx.x;   // 128*256 = 32768
  int idx = gid;
  #pragma unroll
  for (int rep = 0; rep < 2; ++rep, idx += 32768) {  // 2*64*512 = 65536 items
    int side = idx >> 15, rem = idx & 32767;
    int b = rem >> 9, k = rem & 511;
    unsigned short v = f2bf((side ? rst : lst)[b*512 + k]);
    (side ? Xr : Xl)[(size_t)b*NT*512 + k] = v;
  }
  exch_w[gid] = 0u;               // 262144 B = 65536 u32
  exch_w[gid + 32768] = 0u;
  if (gid < 64) flags[gid] = 0;
}

// ---------------- gather: emb -> out mid (fp32) + shifted bf16 X ----------------
__global__ void k_gather(const int* __restrict__ tokens, const float* __restrict__ emb,
                         float* __restrict__ out,
                         unsigned short* __restrict__ Xl, unsigned short* __restrict__ Xr) {
  int gid = blockIdx.x * blockDim.x + threadIdx.x;   // 4096*256; 64 thr per row
  int row = gid >> 6;              // b*T + t
  int e0  = (gid & 63) << 3;
  int b = row >> 8, t = row & 255;
  int tok = tokens[row];
  const float* src = emb + (size_t)tok*512 + e0;
  f32x4 v0 = *(const f32x4*)src;
  f32x4 v1 = *(const f32x4*)(src + 4);
  float* o = out + (size_t)row*1536 + 512 + e0;
  *(f32x4*)o = v0;
  *(f32x4*)(o + 4) = v1;
  u32x4 hv;
  hv[0] = (unsigned)f2bf(v0[0]) | ((unsigned)f2bf(v0[1]) << 16);
  hv[1] = (unsigned)f2bf(v0[2]) | ((unsigned)f2bf(v0[3]) << 16);
  hv[2] = (unsigned)f2bf(v1[0]) | ((unsigned)f2bf(v1[1]) << 16);
  hv[3] = (unsigned)f2bf(v1[2]) | ((unsigned)f2bf(v1[3]) << 16);
  if (t < 255)                                    // emb[b][t] -> Xl row t+1
    *(u32x4*)(Xl + (size_t)(row + 1)*512 + e0) = hv;
  if (t >= 1)                                     // emb[b][t] -> Xr row 256-t
    *(u32x4*)(Xr + ((size_t)b*NT + (NT - t))*512 + e0) = hv;
}

// ---------------- recurrence ----------------
// 64 wgs: side s(2) x batch-group g(4, 16 rows) x col-slice q(8, 64 cols).
// W2 col-slice resident in LDS (bf16, XOR-swizzled); W1 slice in registers as B-frags.
// ctx exchanged between the 8 col-slices of a (s,g) group via device-scope atomics.
__global__ __launch_bounds__(256, 1)
void k_recur(const unsigned short* __restrict__ Xl, const unsigned short* __restrict__ Xr,
             const unsigned short* __restrict__ W1T, const unsigned short* __restrict__ W2T,
             unsigned short* exch, int* flags, float* __restrict__ out) {
  int wg = blockIdx.x;             // 64
  int s = wg >> 5, g = (wg >> 3) & 3, q = wg & 7;
  int tid = threadIdx.x;
  int w = tid >> 6, l = tid & 63;
  int l15 = l & 15, l64 = l >> 4;

  const unsigned short* X  = s ? Xr : Xl;
  const unsigned short* W1 = W1T + (size_t)s*262144;
  const unsigned short* W2 = W2T + (size_t)s*262144;

  __shared__ unsigned char w2lds[65536];   // [64 cols][1024B of k], swizzled
  __shared__ unsigned char ctxlds[16384];  // [16 rows][1024B of k], swizzled

  // fill w2lds: 4096 granules of 16B; swizzle byte ^= ((col&7)<<4)
  for (int i = 0; i < 16; ++i) {
    int gi = tid + i*256;
    int c = gi >> 6, g16 = gi & 63;
    int kb = g16 << 4;
    const unsigned char* sp = (const unsigned char*)W2 + ((size_t)(q*64 + c))*1024 + kb;
    *(u32x4*)&w2lds[c*1024 + (kb ^ ((c & 7) << 4))] = *(const u32x4*)sp;
  }

  // W1 B-frags in registers: frag(kk) = W1T[ncol][kk*32 + l64*8 .. +7]
  u32x4 w1f[16];
  int ncol = q*64 + w*16 + l15;            // global output column
  #pragma unroll
  for (int kk = 0; kk < 16; ++kk)
    w1f[kk] = *(const u32x4*)(W1 + (size_t)ncol*512 + kk*32 + l64*8);

  // X A-frag prefetch for t=0: A row = batch = g*16 + l15
  const unsigned short* Xrow = X + (size_t)(g*16 + l15)*NT*512;
  u32x4 xf[16];
  #pragma unroll
  for (int kk = 0; kk < 16; ++kk)
    xf[kk] = *(const u32x4*)(Xrow + kk*32 + l64*8);

  unsigned short* exg = exch + (size_t)(s*4 + g) * (2*16*512);
  int* flagp = flags + (s*4 + g)*8;
  float* outp = out + (s ? 1024 : 0);
  __syncthreads();

  for (int t = 0; t < 256; ++t) {
    // ---- P-part: acc = X_t @ W1 (no cross-wg dependency; hides partner lag)
    f32x4 acc = {0.f, 0.f, 0.f, 0.f};
    #pragma unroll
    for (int kk = 0; kk < 16; ++kk)
      acc = __builtin_amdgcn_mfma_f32_16x16x32_bf16(
          __builtin_bit_cast(s16x8, xf[kk]), __builtin_bit_cast(s16x8, w1f[kk]), acc, 0, 0, 0);

    // ---- wait for partners' ctx_{t-1}
    if (tid < 8 && tid != q) {
      while (__hip_atomic_load(&flagp[tid], __ATOMIC_RELAXED, __HIP_MEMORY_SCOPE_AGENT) < t)
        __builtin_amdgcn_s_sleep(1);
    }
    __syncthreads();

    // ---- stage ctx_{t-1} (exch slot (t+1)&1) into ctxlds, swizzled, cache-bypassing
    {
      const unsigned char* exr = (const unsigned char*)(exg + ((t + 1) & 1) * (16*512));
      #pragma unroll
      for (int i = 0; i < 4; ++i) {
        int gi = tid + i*256;              // 1024 granules of 16B
        int row = gi >> 6, g16 = gi & 63;
        int kb = g16 << 4;
        unsigned long long lo = __hip_atomic_load(
            (unsigned long long*)(exr + row*1024 + kb), __ATOMIC_RELAXED, __HIP_MEMORY_SCOPE_AGENT);
        unsigned long long hi = __hip_atomic_load(
            (unsigned long long*)(exr + row*1024 + kb + 8), __ATOMIC_RELAXED, __HIP_MEMORY_SCOPE_AGENT);
        int dst = row*1024 + (kb ^ ((row & 7) << 4));
        *(unsigned long long*)&ctxlds[dst] = lo;
        *(unsigned long long*)&ctxlds[dst + 8] = hi;
      }
    }
    __syncthreads();

    // ---- prefetch next X frags (covered by ctx-part + tanh)
    {
      int tn = (t < 255) ? t + 1 : 255;
      #pragma unroll
      for (int kk = 0; kk < 16; ++kk)
        xf[kk] = *(const u32x4*)(Xrow + (size_t)tn*512 + kk*32 + l64*8);
    }

    // ---- ctx-part: acc += ctx_{t-1} @ W2 (A from ctxlds, B from w2lds)
    int c = w*16 + l15;
    #pragma unroll
    for (int kk = 0; kk < 16; ++kk) {
      int kb = kk*64 + l64*16;
      s16x8 a = *(const s16x8*)&ctxlds[l15*1024 + (kb ^ ((l15 & 7) << 4))];
      s16x8 b = *(const s16x8*)&w2lds[c*1024 + (kb ^ ((c & 7) << 4))];
      acc = __builtin_amdgcn_mfma_f32_16x16x32_bf16(a, b, acc, 0, 0, 0);
    }

    // ---- tanh, write output, publish ctx_t
    unsigned short* exw = exg + (t & 1) * (16*512);
    #pragma unroll
    for (int r = 0; r < 4; ++r) {
      int row = l64*4 + r;                 // D layout: row=(l>>4)*4+r, col=l&15
      int b = g*16 + row;
      float x = acc[r];
      float aa = fabsf(x);
      float e = __expf(-2.0f * aa);
      float th = __fdividef(1.0f - e, 1.0f + e);
      th = copysignf(th, x);
      outp[((size_t)b*NT + t)*1536 + ncol] = th;
      __hip_atomic_store(&exw[row*512 + ncol], f2bf(th),
                         __ATOMIC_RELAXED, __HIP_MEMORY_SCOPE_AGENT);
    }
    __syncthreads();
    if (tid == 0)
      __hip_atomic_store(&flagp[q], t + 1, __ATOMIC_RELEASE, __HIP_MEMORY_SCOPE_AGENT);
  }
}

// ---------------- launch ----------------
extern "C" void kernel_launch(void* const* d_in, const int* in_sizes, int n_in,
                              void* d_out, int out_size, void* d_ws, size_t ws_size,
                              hipStream_t stream) {
  const int*   tokens = (const int*)  d_in[0];
  const float* emb    = (const float*)d_in[1];
  const float* Wl1    = (const float*)d_in[2];
  const float* Wl2    = (const float*)d_in[3];
  const float* Wr1    = (const float*)d_in[4];
  const float* Wr2    = (const float*)d_in[5];
  const float* lst    = (const float*)d_in[6];
  const float* rst    = (const float*)d_in[7];
  float* out = (float*)d_out;
  unsigned char* ws = (unsigned char*)d_ws;

  unsigned short* Xl   = (unsigned short*)(ws + XL_OFF);
  unsigned short* Xr   = (unsigned short*)(ws + XR_OFF);
  unsigned short* W1T  = (unsigned short*)(ws + W1T_OFF);
  unsigned short* W2T  = (unsigned short*)(ws + W2T_OFF);
  unsigned short* exch = (unsigned short*)(ws + EXCH_OFF);
  int* flags           = (int*)(ws + FLAG_OFF);

  hipLaunchKernelGGL(k_prep_w,    dim3(256),  dim3(256), 0, stream, Wl1, Wl2, Wr1, Wr2, W1T, W2T);
  hipLaunchKernelGGL(k_prep_misc, dim3(128),  dim3(256), 0, stream, lst, rst, Xl, Xr,
                     (unsigned int*)exch, flags);
  hipLaunchKernelGGL(k_gather,    dim3(4096), dim3(256), 0, stream, tokens, emb, out, Xl, Xr);
  hipLaunchKernelGGL(k_recur,     dim3(64),   dim3(256), 0, stream, Xl, Xr, W1T, W2T,
                     exch, flags, out);
}

// Round 7
// 728.059 us; speedup vs baseline: 2.3722x; 2.3722x over previous
//
#include <hip/hip_runtime.h>
#include <stdint.h>

typedef __attribute__((ext_vector_type(4))) float f32x4;
typedef __attribute__((ext_vector_type(8))) short s16x8;
typedef __attribute__((ext_vector_type(4))) unsigned int u32x4;

#define NT 256
// B=64, T=256, E=H=512

// ---- ws layout (bytes) ----
// W1F: bf16 B-frag order [s][nblk32][kblk16][lane64][8]            = 1 MB
// W2F: fp8  B-frag order [s][wv8][nt4][kk16][lane64][8B] identity  = 0.5 MB
// P:   bf16 D-frag order [sg8][t256][slot16][lane64][8]            = 33.55 MB
static constexpr size_t W1F_OFF = 0;
static constexpr size_t W2F_OFF = W1F_OFF + (size_t)2*512*512*2;
static constexpr size_t P_OFF   = W2F_OFF + (size_t)2*512*512*1;
// total = 35.1 MB

__device__ __forceinline__ unsigned short f2bf(float f) {
  unsigned u = __builtin_bit_cast(unsigned, f);
  u += 0x7fffu + ((u >> 16) & 1u);
  return (unsigned short)(u >> 16);
}
__device__ __forceinline__ unsigned pkbf(float a, float b) {
  return (unsigned)f2bf(a) | ((unsigned)f2bf(b) << 16);
}

// ---------------- prep: weights into fragment layouts ----------------
// grid = 512 blocks: bid<256 -> W1F (65536 granules); bid in [256,512) -> W2F (65536 granules).
// (Round-5 bug: only 128 W2F blocks -> s=1 half of W2F left as 0xAA poison -> -1 ctx lock.)
__global__ void k_prep_w(const float* __restrict__ Wl1, const float* __restrict__ Wl2,
                         const float* __restrict__ Wr1, const float* __restrict__ Wr2,
                         unsigned short* __restrict__ W1F, unsigned char* __restrict__ W2F) {
  int bid = blockIdx.x;
  int tid = threadIdx.x;
  if (bid < 256) {
    // W1F: granule g = ((s*32+nblk)*16+kblk)*64+lane ; value = W1[k][n] bf16
    unsigned g = bid * 256 + tid;                 // 65536 granules
    int lane = g & 63, kblk = (g >> 6) & 15, nblk = (g >> 10) & 31, s = g >> 15;
    const float* src = s ? Wr1 : Wl1;
    int n  = nblk * 16 + (lane & 15);
    int k0 = kblk * 32 + (lane >> 4) * 8;
    unsigned w[4];
    #pragma unroll
    for (int j = 0; j < 4; ++j)
      w[j] = pkbf(src[(size_t)(k0 + 2*j) * 512 + n], src[(size_t)(k0 + 2*j + 1) * 512 + n]);
    u32x4 v = {w[0], w[1], w[2], w[3]};
    *(u32x4*)(W1F + (size_t)g * 8) = v;
  } else {
    // W2F fp8: granule g = (((s*8+wv)*4+nt)*16+kk)*64+lane ; byte j = e4m3(W2[k][n])
    // STANDARD identity layout: position p = (lane>>4)*8+j  ->  k = kk*32 + p
    unsigned g = (bid - 256) * 256 + tid;         // 65536 granules
    int lane = g & 63, kk = (g >> 6) & 15, nt = (g >> 10) & 3, wv = (g >> 12) & 7, s = g >> 15;
    const float* src = s ? Wr2 : Wl2;
    int n  = wv * 64 + nt * 16 + (lane & 15);
    int p0 = (lane >> 4) * 8;
    float v[8];
    #pragma unroll
    for (int j = 0; j < 8; ++j) {
      int c = kk * 32 + p0 + j;                   // identity k-map
      v[j] = src[(size_t)c * 512 + n];
    }
    int lo = __builtin_amdgcn_cvt_pk_fp8_f32(v[0], v[1], 0, false);
    lo     = __builtin_amdgcn_cvt_pk_fp8_f32(v[2], v[3], lo, true);
    int hi = __builtin_amdgcn_cvt_pk_fp8_f32(v[4], v[5], 0, false);
    hi     = __builtin_amdgcn_cvt_pk_fp8_f32(v[6], v[7], hi, true);
    unsigned long long pk = (unsigned)lo | ((unsigned long long)(unsigned)hi << 32);
    *(unsigned long long*)(W2F + (size_t)g * 8) = pk;
  }
}

// ---------------- gather: emb -> out middle slice (fp32, exact) ----------------
__global__ void k_gather(const int* __restrict__ tokens, const float* __restrict__ emb,
                         float* __restrict__ out) {
  int gid = blockIdx.x * blockDim.x + threadIdx.x;   // 4096*256; 64 thr per row
  int row = gid >> 6;              // b*T + t
  int e0  = (gid & 63) << 3;
  int tok = tokens[row];
  const float* src = emb + (size_t)tok * 512 + e0;
  f32x4 v0 = *(const f32x4*)src;
  f32x4 v1 = *(const f32x4*)(src + 4);
  float* o = out + (size_t)row * 1536 + 512 + e0;
  *(f32x4*)o = v0;
  *(f32x4*)(o + 4) = v1;
}

// ---------------- P = X @ W1 (token-gathered A, bf16 MFMA, bf16 D-frag out) ----------------
// X row b of tile (s,t): t==0 -> state[b]; left: emb[tok[b][t-1]]; right: emb[tok[b][256-t]]
__global__ __launch_bounds__(256, 3)
void k_pgemm(const int* __restrict__ tokens, const float* __restrict__ emb,
             const float* __restrict__ lst, const float* __restrict__ rst,
             const unsigned short* __restrict__ W1F, unsigned short* __restrict__ P) {
  int wg = blockIdx.x;                  // 2048 = s(2) x t(256) x nq(4)
  int nq = wg & 3, t = (wg >> 2) & 255, s = wg >> 10;
  int tid = threadIdx.x, g = tid >> 6, l = tid & 63;

  __shared__ unsigned short Abuf[2][8 * 64 * 8];    // [chunk=bblk*2+kk][lane][8]
  __shared__ unsigned short Bbuf[2][16 * 64 * 8];   // [chunk=nloc*2+kk][lane][8]
  __shared__ unsigned long long rowsrc[64];

  if (tid < 64) {
    const float* base;
    if (t == 0) base = (s ? rst : lst) + (size_t)tid * 512;
    else {
      int tp = s ? (256 - t) : (t - 1);
      base = emb + (size_t)tokens[tid * 256 + tp] * 512;
    }
    rowsrc[tid] = (unsigned long long)base;
  }

  const unsigned short* Bs = W1F + ((size_t)(s * 32 + nq * 8) * 16) * 512;
  int bN[4], bK[4], bL[4];
  #pragma unroll
  for (int j = 0; j < 4; ++j) {
    int gB = tid + j * 256;
    bN[j] = (gB >> 7) * 16; bK[j] = (gB >> 6) & 1; bL[j] = gB & 63;
  }
  // A staging coords: thread covers row=tid>>2, k = kt*64 + (tid&3)*16 .. +15
  int arow = tid >> 2, kq = tid & 3;
  int aChunk = (arow >> 4) * 2 + (kq >> 1);
  int aOff0 = (aChunk * 64 + (((kq * 2) & 3) << 4) + (arow & 15)) * 8;
  int aOff1 = (aChunk * 64 + (((kq * 2 + 1) & 3) << 4) + (arow & 15)) * 8;
  __syncthreads();                                  // rowsrc visible
  const float* aSrc = (const float*)rowsrc[arow] + kq * 16;

  f32x4 acc[8];
  #pragma unroll
  for (int n = 0; n < 8; ++n) acc[n] = (f32x4){0.f, 0.f, 0.f, 0.f};

  f32x4 q0, q1, q2, q3;
  u32x4 br[4];
  // prologue: stage kt=0
  q0 = *(const f32x4*)(aSrc);     q1 = *(const f32x4*)(aSrc + 4);
  q2 = *(const f32x4*)(aSrc + 8); q3 = *(const f32x4*)(aSrc + 12);
  #pragma unroll
  for (int j = 0; j < 4; ++j)
    br[j] = *(const u32x4*)(Bs + (size_t)(bN[j] + bK[j]) * 512 + bL[j] * 8);
  {
    u32x4 h0 = {pkbf(q0[0],q0[1]), pkbf(q0[2],q0[3]), pkbf(q1[0],q1[1]), pkbf(q1[2],q1[3])};
    u32x4 h1 = {pkbf(q2[0],q2[1]), pkbf(q2[2],q2[3]), pkbf(q3[0],q3[1]), pkbf(q3[2],q3[3])};
    *(u32x4*)&Abuf[0][aOff0] = h0;
    *(u32x4*)&Abuf[0][aOff1] = h1;
  }
  #pragma unroll
  for (int j = 0; j < 4; ++j) *(u32x4*)&Bbuf[0][(tid + j * 256) * 8] = br[j];
  __syncthreads();

  int buf = 0;
  for (int kt = 0; kt < 8; ++kt) {
    if (kt < 7) {   // issue next-tile loads
      const float* p = aSrc + (kt + 1) * 64;
      q0 = *(const f32x4*)(p);     q1 = *(const f32x4*)(p + 4);
      q2 = *(const f32x4*)(p + 8); q3 = *(const f32x4*)(p + 12);
      int ko = (kt + 1) * 2;
      #pragma unroll
      for (int j = 0; j < 4; ++j)
        br[j] = *(const u32x4*)(Bs + (size_t)(bN[j] + ko + bK[j]) * 512 + bL[j] * 8);
    }
    // compute current
    #pragma unroll
    for (int kk = 0; kk < 2; ++kk) {
      s16x8 a = *(const s16x8*)&Abuf[buf][(g * 2 + kk) * 512 + l * 8];
      #pragma unroll
      for (int n = 0; n < 8; ++n) {
        s16x8 b = *(const s16x8*)&Bbuf[buf][(n * 2 + kk) * 512 + l * 8];
        acc[n] = __builtin_amdgcn_mfma_f32_16x16x32_bf16(a, b, acc[n], 0, 0, 0);
      }
    }
    if (kt < 7) {
      u32x4 h0 = {pkbf(q0[0],q0[1]), pkbf(q0[2],q0[3]), pkbf(q1[0],q1[1]), pkbf(q1[2],q1[3])};
      u32x4 h1 = {pkbf(q2[0],q2[1]), pkbf(q2[2],q2[3]), pkbf(q3[0],q3[1]), pkbf(q3[2],q3[3])};
      *(u32x4*)&Abuf[buf ^ 1][aOff0] = h0;
      *(u32x4*)&Abuf[buf ^ 1][aOff1] = h1;
      #pragma unroll
      for (int j = 0; j < 4; ++j) *(u32x4*)&Bbuf[buf ^ 1][(tid + j * 256) * 8] = br[j];
      __syncthreads();
      buf ^= 1;
    }
  }

  // epilogue: pack D-frags to bf16, store in P perm layout
  size_t sg = (size_t)s * 4 + g;
  #pragma unroll
  for (int m = 0; m < 4; ++m) {
    u32x4 v;
    v[0] = pkbf(acc[2*m][0],   acc[2*m][1]);
    v[1] = pkbf(acc[2*m][2],   acc[2*m][3]);
    v[2] = pkbf(acc[2*m+1][0], acc[2*m+1][1]);
    v[3] = pkbf(acc[2*m+1][2], acc[2*m+1][3]);
    int slot = (nq * 2 + (m >> 1)) * 2 + (m & 1);
    *(u32x4*)(P + ((sg * 256 + t) * 16 + slot) * 512 + l * 8) = v;
  }
}

// ---------------- recurrence: ctx_t = tanh(P_t + ctx_{t-1} @ W2), fp8 W2 in VGPRs ----------------
// 8 wgs = 2 sides x 4 batch-groups(16 rows); 512 thr = 8 waves; wave wv owns cols wv*64..+63.
// ctx fp8 ROW-MAJOR in LDS (identity k-map), double-buffered -> ONE barrier per step.
__global__ __launch_bounds__(512, 2)
void k_recur(const unsigned short* __restrict__ P, const unsigned char* __restrict__ W2F,
             float* __restrict__ out) {
  int wg = blockIdx.x;             // 8
  int s = wg >> 2, gq = wg & 3;
  int tid = threadIdx.x;
  int wv = tid >> 6, l = tid & 63, l15 = l & 15, l64 = l >> 4;

  __shared__ unsigned char ctxb[2][16 * 528];   // fp8 ctx row-major, row stride 528B

  for (int i = tid; i < 2 * 16 * 528 / 4; i += 512) ((unsigned*)&ctxb[0][0])[i] = 0;

  // W2 fragments -> registers: [nt4][kk16] of 8 bytes
  long long w2[4][16];
  const unsigned long long* wp =
      (const unsigned long long*)W2F + (size_t)(s * 8 + wv) * 4096 + l;
  #pragma unroll
  for (int nt = 0; nt < 4; ++nt)
    #pragma unroll
    for (int kk = 0; kk < 16; ++kk)
      w2[nt][kk] = (long long)wp[(nt * 16 + kk) * 64];

  size_t sg = (size_t)s * 4 + gq;
  const unsigned short* Pp = P + (sg * 256) * 16 * 512 + (wv * 2) * 512 + l * 8;
  // out base: row b = gq*16 + l64*4 + r, col = (s?1024:0) + wv*64 + nt*16 + l15
  float* outb = out + (s ? 1024 : 0) + ((size_t)(gq * 16 + l64 * 4) * 256) * 1536
              + wv * 64 + l15;

  u32x4 pf0 = *(const u32x4*)(Pp);
  u32x4 pf1 = *(const u32x4*)(Pp + 512);
  __syncthreads();                 // zero-init + prologue visible

  float th[4][4];
  for (int t = 0; t < 256; ++t) {
    // acc init from P (bf16 -> f32 via bit shift); acc[nt], nt = 2j+ii
    f32x4 acc[4];
    #pragma unroll
    for (int j = 0; j < 2; ++j) {
      u32x4 pf = j ? pf1 : pf0;
      #pragma unroll
      for (int ii = 0; ii < 2; ++ii)
        #pragma unroll
        for (int r = 0; r < 4; ++r) {
          unsigned wrd = pf[ii * 2 + (r >> 1)];
          unsigned bits = (r & 1) ? (wrd & 0xffff0000u) : (wrd << 16);
          acc[2 * j + ii][r] = __builtin_bit_cast(float, bits);
        }
    }
    // prefetch P for t+1 NOW (issue-to-use gap = one full step)
    if (t < 255) {
      pf0 = *(const u32x4*)(Pp + (size_t)(t + 1) * 8192);
      pf1 = *(const u32x4*)(Pp + (size_t)(t + 1) * 8192 + 512);
    }
    // ctx_{t-1} @ W2 (fp8, standard layout), read slot (t+1)&1
    // A lane l: row = l15, k = kk*32 + l64*8 + j  (row-major ctx -> contiguous 8B)
    const unsigned char* cr = ctxb[(t + 1) & 1];
    #pragma unroll
    for (int kk = 0; kk < 16; ++kk) {
      long long a = *(const long long*)&cr[l15 * 528 + kk * 32 + l64 * 8];
      #pragma unroll
      for (int nt = 0; nt < 4; ++nt)
        acc[nt] = __builtin_amdgcn_mfma_f32_16x16x32_fp8_fp8(a, w2[nt][kk], acc[nt], 0, 0, 0);
    }
    // tanh
    #pragma unroll
    for (int nt = 0; nt < 4; ++nt)
      #pragma unroll
      for (int r = 0; r < 4; ++r) {
        float x = acc[nt][r];
        float ax = __builtin_fabsf(x);
        float e = __expf(ax * -2.0f);
        float v = (1.0f - e) * __builtin_amdgcn_rcpf(1.0f + e);
        th[nt][r] = __builtin_copysignf(v, x);
      }
    // publish ctx_t row-major: byte[row*528 + h] = fp8(ctx[h]), h = wv*64+nt*16+l15
    unsigned char* cw = ctxb[t & 1];
    #pragma unroll
    for (int nt = 0; nt < 4; ++nt)
      #pragma unroll
      for (int r = 0; r < 4; ++r) {
        int pk = __builtin_amdgcn_cvt_pk_fp8_f32(th[nt][r], th[nt][r], 0, false);
        cw[(l64 * 4 + r) * 528 + wv * 64 + nt * 16 + l15] = (unsigned char)pk;
      }
    __syncthreads();               // ctx_t visible; reads of ctx_{t-1} all completed before
    // out stores after the barrier -> overlap next step's MFMA
    #pragma unroll
    for (int nt = 0; nt < 4; ++nt)
      #pragma unroll
      for (int r = 0; r < 4; ++r)
        outb[((size_t)r * 256 + t) * 1536 + nt * 16] = th[nt][r];
  }
}

// ---------------- launch ----------------
extern "C" void kernel_launch(void* const* d_in, const int* in_sizes, int n_in,
                              void* d_out, int out_size, void* d_ws, size_t ws_size,
                              hipStream_t stream) {
  const int*   tokens = (const int*)  d_in[0];
  const float* emb    = (const float*)d_in[1];
  const float* Wl1    = (const float*)d_in[2];
  const float* Wl2    = (const float*)d_in[3];
  const float* Wr1    = (const float*)d_in[4];
  const float* Wr2    = (const float*)d_in[5];
  const float* lst    = (const float*)d_in[6];
  const float* rst    = (const float*)d_in[7];
  float* out = (float*)d_out;
  unsigned char* ws = (unsigned char*)d_ws;

  unsigned short* W1F = (unsigned short*)(ws + W1F_OFF);
  unsigned char*  W2F = (unsigned char*)(ws + W2F_OFF);
  unsigned short* P   = (unsigned short*)(ws + P_OFF);

  hipLaunchKernelGGL(k_prep_w, dim3(512),  dim3(256), 0, stream, Wl1, Wl2, Wr1, Wr2, W1F, W2F);
  hipLaunchKernelGGL(k_gather, dim3(4096), dim3(256), 0, stream, tokens, emb, out);
  hipLaunchKernelGGL(k_pgemm,  dim3(2048), dim3(256), 0, stream, tokens, emb, lst, rst, W1F, P);
  hipLaunchKernelGGL(k_recur,  dim3(8),    dim3(512), 0, stream, P, W2F, out);
}